// Round 3
// baseline (449.770 us; speedup 1.0000x reference)
//
#include <hip/hip_runtime.h>

#define NZ    4000
#define NPAD  100
#define NZP   4100      // NZ + NPAD
#define NROW  8192      // 128 vels * 64 shots
#define NGRP  1025      // NZP / 4

__global__ __launch_bounds__(256) void prop1d(
    const float* __restrict__ vel,     // [128, 4000] f32
    const float* __restrict__ wavelet, // [128] f32
    const int*   __restrict__ zs,      // [8192] int32, in [0,4000)
    const int*   __restrict__ zr,      // [8192] int32, in [0,4000)
    const float* __restrict__ prev,    // [8192, 4100] f32
    const float* __restrict__ curr,    // [8192, 4100] f32
    float* __restrict__ out0,          // curr passthrough (f32)
    float* __restrict__ out1,          // u_next (f32)
    float* __restrict__ out2,          // yt [8192] (f32)
    float* __restrict__ out3)          // regularizer [1] (f32)
{
    __shared__ float sc[NZP + 8];   // curr row; data at [4, 4+NZP), zero halo both sides
    const int row = blockIdx.x;     // v*64 + s
    const int v   = row >> 6;
    const int tid = threadIdx.x;

    const float* crow = curr + (size_t)row * NZP;
    const float* prow = prev + (size_t)row * NZP;
    float* o0 = out0 + (size_t)row * NZP;
    float* o1 = out1 + (size_t)row * NZP;

    if (tid < 8) sc[(tid < 4) ? tid : (NZP + tid)] = 0.0f;  // [0..3], [4104..4107]

    // stage curr row into LDS (float4 global loads; rows are 16400 B, 16-aligned)
    for (int g = tid; g < NGRP; g += 256) {
        *(float4*)(&sc[4 + 4 * g]) = *(const float4*)(crow + 4 * g);
    }
    __syncthreads();

    const int   zsr = zs[row];
    const int   zrr = zr[row];
    const float wf  = wavelet[v];

    // stencil taps: C4 = (dt/dz)^2 / 12 in double, rounded to f32 (matches np)
    const double C4d = (0.001 / 5.0) * (0.001 / 5.0) / 12.0;
    const float c0 = (float)(-C4d);
    const float c1 = (float)(16.0 * C4d);
    const float c2 = (float)(-30.0 * C4d);

    for (int g = tid; g < NGRP; g += 256) {
        const int zb = 4 * g;                 // first z of this group
        // curr[zb-2 .. zb+5] from LDS (data offset +4 -> index zb+2 .. zb+9)
        float u0 = sc[zb + 2], u1 = sc[zb + 3], u2 = sc[zb + 4], u3 = sc[zb + 5];
        float u4 = sc[zb + 6], u5 = sc[zb + 7], u6 = sc[zb + 8], u7 = sc[zb + 9];

        float4 pv = *(const float4*)(prow + zb);

        float w0, w1, w2, w3;                 // vel^2 (edge-padded past NZ)
        if (g < 1000) {                       // zb+3 <= 3999
            float4 vv = *(const float4*)(vel + v * NZ + zb);
            w0 = vv.x * vv.x; w1 = vv.y * vv.y; w2 = vv.z * vv.z; w3 = vv.w * vv.w;
        } else {                              // zb >= 4000 -> edge value
            float a = vel[v * NZ + (NZ - 1)];
            w0 = w1 = w2 = w3 = a * a;
        }

        float l0 = c0 * (u0 + u4) + c1 * (u1 + u3) + c2 * u2;
        float l1 = c0 * (u1 + u5) + c1 * (u2 + u4) + c2 * u3;
        float l2 = c0 * (u2 + u6) + c1 * (u3 + u5) + c2 * u4;
        float l3 = c0 * (u3 + u7) + c1 * (u4 + u6) + c2 * u5;

        float n0 = l0 * w0 + 2.0f * u2 - pv.x;
        float n1 = l1 * w1 + 2.0f * u3 - pv.y;
        float n2 = l2 * w2 + 2.0f * u4 - pv.z;
        float n3 = l3 * w3 + 2.0f * u5 - pv.w;

        if (g < 1000) {
            // source injection (zs < 4000 where sponge mask == 1)
            int d = zsr - zb;
            if ((unsigned)d < 4u) {
                if      (d == 0) n0 += wf;
                else if (d == 1) n1 += wf;
                else if (d == 2) n2 += wf;
                else             n3 += wf;
            }
        } else {
            // sponge: z >= 4000 -> exp(-(0.0015^2) * (z-3999)^2)
            float k0 = (float)(zb - (NZ - 1));
            float k1 = k0 + 1.0f, k2 = k0 + 2.0f, k3 = k0 + 3.0f;
            n0 *= expf(-2.25e-6f * k0 * k0);
            n1 *= expf(-2.25e-6f * k1 * k1);
            n2 *= expf(-2.25e-6f * k2 * k2);
            n3 *= expf(-2.25e-6f * k3 * k3);
        }

        // receiver readout (zr < 4000; mask==1 there)
        {
            int d = zrr - zb;
            if ((unsigned)d < 4u) {
                out2[row] = (d == 0) ? n0 : (d == 1) ? n1 : (d == 2) ? n2 : n3;
            }
        }

        // stores (f32): out0 = curr passthrough, out1 = u_next
        float4 cs; cs.x = u2; cs.y = u3; cs.z = u4; cs.w = u5;
        *(float4*)(o0 + zb) = cs;
        float4 ns; ns.x = n0; ns.y = n1; ns.z = n2; ns.w = n3;
        *(float4*)(o1 + zb) = ns;
    }

    if (row == 0 && tid == 0) out3[0] = 0.0f;  // regularizer = 0
}

extern "C" void kernel_launch(void* const* d_in, const int* in_sizes, int n_in,
                              void* d_out, int out_size, void* d_ws, size_t ws_size,
                              hipStream_t stream) {
    const float* vel     = (const float*)d_in[0];
    const float* wavelet = (const float*)d_in[1];
    const int*   zs      = (const int*)d_in[2];
    const int*   zr      = (const int*)d_in[3];
    const float* prev    = (const float*)d_in[4];
    const float* curr    = (const float*)d_in[5];

    float* out0 = (float*)d_out;                       // [8192*4100]
    float* out1 = out0 + (size_t)NROW * NZP;           // [8192*4100]
    float* out2 = out1 + (size_t)NROW * NZP;           // [8192]
    float* out3 = out2 + NROW;                         // [1]

    prop1d<<<NROW, 256, 0, stream>>>(vel, wavelet, zs, zr, prev, curr,
                                     out0, out1, out2, out3);
}